// Round 4
// baseline (250.090 us; speedup 1.0000x reference)
//
#include <hip/hip_runtime.h>
#include <hip/hip_bf16.h>

#define S_LEN 1024
#define DIN 4096
#define NH 32
#define NG 8
#define HD 128

typedef __bf16 bf16x8 __attribute__((ext_vector_type(8)));
typedef __bf16 bf16x4 __attribute__((ext_vector_type(4)));
typedef float f32x4 __attribute__((ext_vector_type(4)));

__device__ __forceinline__ void gload_lds16(const void* g, void* l) {
  __builtin_amdgcn_global_load_lds(
      (const __attribute__((address_space(1))) unsigned int*)g,
      (__attribute__((address_space(3))) unsigned int*)l, 16, 0, 0);
}

__device__ __forceinline__ unsigned pack2bf(float a, float b) {
  union { __bf16 h[2]; unsigned u; } x;
  x.h[0] = (__bf16)a; x.h[1] = (__bf16)b;
  return x.u;
}

// ---------------- cast x: f32 -> bf16 ----------------
__global__ __launch_bounds__(256) void k_cast(const float* __restrict__ in,
                                              __bf16* __restrict__ out, int n4) {
  int i = blockIdx.x * 256 + threadIdx.x;
  if (i >= n4) return;
  const float4 v = ((const float4*)in)[i];
  bf16x4 o;
  o.x = (__bf16)v.x; o.y = (__bf16)v.y; o.z = (__bf16)v.z; o.w = (__bf16)v.w;
  ((bf16x4*)out)[i] = o;
}

// ---------------- RoPE in-place on Q (NH heads) and K (NG heads) ----------------
__global__ __launch_bounds__(256) void k_rope(__bf16* __restrict__ Q, __bf16* __restrict__ Kb,
                                              const float* __restrict__ cosT,
                                              const float* __restrict__ sinT) {
  int idx = blockIdx.x * 256 + threadIdx.x;
  const int QP = S_LEN * NH * 64;
  __bf16* t; int nh;
  if (idx < QP) { t = Q; nh = NH; }
  else {
    idx -= QP; t = Kb; nh = NG;
    if (idx >= S_LEN * NG * 64) return;
  }
  int d = idx & 63;
  int h = (idx >> 6) % nh;
  int s = idx / (64 * nh);
  float c = cosT[s * HD + d], sn = sinT[s * HD + d];
  size_t base = (size_t)s * nh * HD + h * HD + d;
  float t1 = (float)t[base], t2 = (float)t[base + 64];
  t[base]      = (__bf16)(t1 * c - t2 * sn);
  t[base + 64] = (__bf16)(t2 * c + t1 * sn);
}

// ---------------- GEMM: C(M,N) = A(M,K,bf16) * W(K,N,f32) ----------------
// BM=128, BN=64, BK=64. 4 waves, wave w owns rows [w*32, w*32+32), all 64 cols.
// A: gload_lds-staged bf16, 3-bit XOR chunk swizzle (round-2 proven, 0 conflicts).
// B: gload_lds-staged RAW f32 tile [64 k][64 n dwords], source pre-swizzled so
//    LDS dword col' = n ^ (((k>>3)&3)<<3). NO per-lane LDS writes anywhere.
//    Fragment build: 8 f32 reads (k-pairs, ds_read2) at bank = col'%32 ->
//    2-way uniform (free), then cast to bf16 in-register.
// MODE 0: f32 C output (N=4096). MODE 1: QKV split epilogue (Q,K bf16; V transposed).
template <int MODE>
__global__ __launch_bounds__(256, 3) void k_gemm(const __bf16* __restrict__ A,
                                                 const float* __restrict__ W0,
                                                 const float* __restrict__ W1,
                                                 const float* __restrict__ W2,
                                                 float* __restrict__ C,
                                                 __bf16* __restrict__ Qb,
                                                 __bf16* __restrict__ Kb,
                                                 __bf16* __restrict__ Vt) {
  __shared__ __bf16 As[128 * 64];
  __shared__ float Bf[64 * 64];
  const int bm = blockIdx.y, bn = blockIdx.x;
  const int K = DIN, NT = K / 64;

  const float* Wsrc; int ldb, nloc;
  if (MODE == 0) { Wsrc = W0; ldb = 4096; nloc = bn * 64; }
  else {
    if (bn < 64)      { Wsrc = W0; ldb = 4096; nloc = bn * 64; }
    else if (bn < 80) { Wsrc = W1; ldb = 1024; nloc = (bn - 64) * 64; }
    else              { Wsrc = W2; ldb = 1024; nloc = (bn - 80) * 64; }
  }

  const int tid = threadIdx.x, w = tid >> 6;
  const int l = tid & 63, l15 = l & 15, g4 = l >> 4;

  f32x4 acc[2][4];
#pragma unroll
  for (int i = 0; i < 2; ++i)
#pragma unroll
    for (int j = 0; j < 4; ++j)
#pragma unroll
      for (int r = 0; r < 4; ++r) acc[i][j][r] = 0.f;

  for (int t = 0; t < NT; ++t) {
    // ---- stage A (128x64 bf16) via DMA, 3-bit XOR chunk swizzle ----
    const __bf16* Ab = A + (size_t)(bm * 128) * K + t * 64;
#pragma unroll
    for (int p = 0; p < 4; ++p) {
      int c = p * 256 + tid;
      int row = c >> 3, gc = (c & 7) ^ (row & 7);
      gload_lds16(Ab + (size_t)row * K + gc * 8, &As[(p * 256 + w * 64) * 8]);
    }
    // ---- stage B (64x64 f32) via DMA; source pre-swizzled (quad XOR) ----
    const float* Wb = Wsrc + (size_t)(t * 64) * ldb + nloc;
#pragma unroll
    for (int p = 0; p < 4; ++p) {
      int c = p * 256 + tid;
      int row = c >> 4, q = c & 15;
      int gq = q ^ (((row >> 3) & 3) << 1);
      gload_lds16(Wb + (size_t)row * ldb + gq * 4, &Bf[(p * 256 + w * 64) * 4]);
    }
    __syncthreads();  // drains both DMAs

    // ---- A fragments (b128, proven conflict-free) ----
    bf16x8 af[2][2];
#pragma unroll
    for (int i = 0; i < 2; ++i) {
      int m = w * 32 + i * 16 + l15;
#pragma unroll
      for (int kk = 0; kk < 2; ++kk)
        af[i][kk] = *(const bf16x8*)((const char*)As + m * 128 + (((kk * 4 + g4) ^ (m & 7)) << 4));
    }
    // ---- B fragments from f32 LDS (2-way banks) + cvt, then MFMA ----
#pragma unroll
    for (int kk = 0; kk < 2; ++kk) {
#pragma unroll
      for (int j = 0; j < 4; ++j) {
        const float* bp = &Bf[(kk * 32 + g4 * 8) * 64 + ((j * 16 + l15) ^ (g4 << 3))];
        bf16x8 bfrag;
#pragma unroll
        for (int d = 0; d < 4; ++d) {
          bfrag[2 * d]     = (__bf16)bp[d * 128];
          bfrag[2 * d + 1] = (__bf16)bp[d * 128 + 64];
        }
#pragma unroll
        for (int i = 0; i < 2; ++i)
          acc[i][j] = __builtin_amdgcn_mfma_f32_16x16x32_bf16(af[i][kk], bfrag, acc[i][j], 0, 0, 0);
      }
    }
    __syncthreads();  // protect LDS from next iteration's staging
  }

  // ---- epilogue ----
  if constexpr (MODE == 0) {
#pragma unroll
    for (int i = 0; i < 2; ++i)
#pragma unroll
      for (int j = 0; j < 4; ++j)
#pragma unroll
        for (int r = 0; r < 4; ++r) {
          size_t row = bm * 128 + w * 32 + i * 16 + g4 * 4 + r;
          size_t col = bn * 64 + j * 16 + l15;
          C[row * 4096 + col] = acc[i][j][r];
        }
  } else {
    if (bn < 80) {
      __bf16* dst = (bn < 64) ? Qb : Kb;
      int ldc = (bn < 64) ? 4096 : 1024;
#pragma unroll
      for (int i = 0; i < 2; ++i)
#pragma unroll
        for (int j = 0; j < 4; ++j)
#pragma unroll
          for (int r = 0; r < 4; ++r) {
            size_t row = bm * 128 + w * 32 + i * 16 + g4 * 4 + r;
            size_t col = nloc + j * 16 + l15;
            dst[row * ldc + col] = (__bf16)acc[i][j][r];
          }
    } else {
      // V: write transposed -> Vt[n][s], 4 consecutive s packed per store
#pragma unroll
      for (int i = 0; i < 2; ++i)
#pragma unroll
        for (int j = 0; j < 4; ++j) {
          size_t n = nloc + j * 16 + l15;
          size_t m0 = bm * 128 + w * 32 + i * 16 + g4 * 4;
          bf16x4 v;
          v.x = (__bf16)acc[i][j][0]; v.y = (__bf16)acc[i][j][1];
          v.z = (__bf16)acc[i][j][2]; v.w = (__bf16)acc[i][j][3];
          *(bf16x4*)&Vt[n * 1024 + m0] = v;
        }
    }
  }
}

// ---------------- flash attention (unchanged, proven) ----------------
__global__ __launch_bounds__(256) void k_attn(const __bf16* __restrict__ Q,
                                              const __bf16* __restrict__ Kb,
                                              const __bf16* __restrict__ Vt,
                                              __bf16* __restrict__ ctx) {
  __shared__ __align__(16) char lds_raw[65536];
  __bf16* Ks = (__bf16*)lds_raw;
  __bf16* Vs = (__bf16*)(lds_raw + 32768);

  const int h = blockIdx.y, g = h >> 2;
  const int q0 = blockIdx.x * 64;
  const int tid = threadIdx.x, w = tid >> 6, l = tid & 63;
  const int l15 = l & 15, g4 = l >> 4;
  const float scale = 0.08838834764831845f;

  bf16x8 qf[4];
  const int qrow = q0 + w * 16 + l15;
#pragma unroll
  for (int ks = 0; ks < 4; ++ks)
    qf[ks] = *(const bf16x8*)&Q[(size_t)qrow * (NH * HD) + h * HD + ks * 32 + g4 * 8];

  f32x4 acc[8];
#pragma unroll
  for (int i = 0; i < 8; ++i)
#pragma unroll
    for (int r = 0; r < 4; ++r) acc[i][r] = 0.f;
  float m_run = -__builtin_inff(), l_run = 0.f;

  const int ntiles = (q0 + 64 + 127) >> 7;
  for (int kt = 0; kt < ntiles; ++kt) {
    const int kv0 = kt * 128;
#pragma unroll
    for (int p = 0; p < 8; ++p) {
      int c = p * 256 + tid;
      int row = c >> 4, cc = c & 15;
      gload_lds16(&Kb[(size_t)(kv0 + row) * (NG * HD) + g * HD + ((cc ^ (row & 7)) << 3)],
                  &Ks[(p * 256 + w * 64) * 8]);
      gload_lds16(&Vt[(size_t)(g * HD + row) * S_LEN + kv0 + ((cc ^ (row & 7)) << 3)],
                  &Vs[(p * 256 + w * 64) * 8]);
    }
    __syncthreads();

    float sreg[8][4];
    const bool need_mask = (kv0 + 127 > q0);
#pragma unroll
    for (int tf = 0; tf < 8; ++tf) {
      f32x4 sa;
#pragma unroll
      for (int r = 0; r < 4; ++r) sa[r] = 0.f;
      int t_loc = tf * 16 + l15;
#pragma unroll
      for (int ks = 0; ks < 4; ++ks) {
        bf16x8 kf = *(const bf16x8*)((const char*)Ks + t_loc * 256 + (((ks * 4 + g4) ^ (t_loc & 7)) << 4));
        sa = __builtin_amdgcn_mfma_f32_16x16x32_bf16(kf, qf[ks], sa, 0, 0, 0);
      }
#pragma unroll
      for (int r = 0; r < 4; ++r) {
        float v = sa[r] * scale;
        if (need_mask && (kv0 + tf * 16 + g4 * 4 + r) > qrow) v = -__builtin_inff();
        sreg[tf][r] = v;
      }
    }
    float mx = -__builtin_inff();
#pragma unroll
    for (int tf = 0; tf < 8; ++tf)
#pragma unroll
      for (int r = 0; r < 4; ++r) mx = fmaxf(mx, sreg[tf][r]);
    mx = fmaxf(mx, __shfl_xor(mx, 16));
    mx = fmaxf(mx, __shfl_xor(mx, 32));
    const float m_new = fmaxf(m_run, mx);
    const float alpha = __expf(m_run - m_new);
    float ssum = 0.f;
#pragma unroll
    for (int tf = 0; tf < 8; ++tf)
#pragma unroll
      for (int r = 0; r < 4; ++r) {
        sreg[tf][r] = __expf(sreg[tf][r] - m_new);
        ssum += sreg[tf][r];
      }
    ssum += __shfl_xor(ssum, 16);
    ssum += __shfl_xor(ssum, 32);
    l_run = l_run * alpha + ssum;
    m_run = m_new;
    float ar[4];
#pragma unroll
    for (int r = 0; r < 4; ++r) ar[r] = __shfl(alpha, g4 * 4 + r);
#pragma unroll
    for (int nf = 0; nf < 8; ++nf)
#pragma unroll
      for (int r = 0; r < 4; ++r) acc[nf][r] *= ar[r];

    __syncthreads();

    char* pb = lds_raw + w * 4096;
#pragma unroll
    for (int tf = 0; tf < 8; ++tf) {
      int chunkc = 2 * tf + (g4 >> 1);
      int addr = l15 * 256 + ((chunkc ^ (l15 & 7)) << 4) + ((g4 & 1) << 3);
      *(unsigned*)(pb + addr)     = pack2bf(sreg[tf][0], sreg[tf][1]);
      *(unsigned*)(pb + addr + 4) = pack2bf(sreg[tf][2], sreg[tf][3]);
    }
    asm volatile("s_waitcnt lgkmcnt(0)" ::: "memory");
    bf16x8 pf[4];
#pragma unroll
    for (int ks = 0; ks < 4; ++ks)
      pf[ks] = *(const bf16x8*)(pb + l15 * 256 + (((ks * 4 + g4) ^ (l15 & 7)) << 4));
#pragma unroll
    for (int nf = 0; nf < 8; ++nf) {
      int d_loc = nf * 16 + l15;
#pragma unroll
      for (int ks = 0; ks < 4; ++ks) {
        bf16x8 vf = *(const bf16x8*)((const char*)Vs + d_loc * 256 + (((ks * 4 + g4) ^ (d_loc & 7)) << 4));
        acc[nf] = __builtin_amdgcn_mfma_f32_16x16x32_bf16(pf[ks], vf, acc[nf], 0, 0, 0);
      }
    }
    __syncthreads();
  }
  float li[4];
#pragma unroll
  for (int r = 0; r < 4; ++r) li[r] = 1.f / __shfl(l_run, g4 * 4 + r);
#pragma unroll
  for (int nf = 0; nf < 8; ++nf)
#pragma unroll
    for (int r = 0; r < 4; ++r) {
      size_t row = q0 + w * 16 + g4 * 4 + r;
      size_t col = (size_t)h * HD + nf * 16 + l15;
      ctx[row * (NH * HD) + col] = (__bf16)(acc[nf][r] * li[r]);
    }
}

// ---------------- host ----------------
extern "C" void kernel_launch(void* const* d_in, const int* in_sizes, int n_in,
                              void* d_out, int out_size, void* d_ws, size_t ws_size,
                              hipStream_t stream) {
  const float* x    = (const float*)d_in[0];
  const float* cosT = (const float*)d_in[2];
  const float* sinT = (const float*)d_in[3];
  const float* Wq   = (const float*)d_in[4];
  const float* Wk   = (const float*)d_in[5];
  const float* Wv   = (const float*)d_in[6];
  const float* Wo   = (const float*)d_in[7];
  float* out = (float*)d_out;

  char* ws = (char*)d_ws;
  const size_t MB = 1u << 20;
  __bf16* xb   = (__bf16*)(ws + 0);        // 8 MB : x bf16; reused as ctx after QKV
  __bf16* Qb   = (__bf16*)(ws + 8 * MB);   // 8 MB : Q (1024 x 4096), roped in-place
  __bf16* Kbuf = (__bf16*)(ws + 16 * MB);  // 2 MB : K (1024 x 1024), roped in-place
  __bf16* Vtb  = (__bf16*)(ws + 18 * MB);  // 2 MB : V^T (1024 x 1024), from epilogue
  __bf16* ctxb = (__bf16*)(ws + 0);        // aliases xb (dead after QKV GEMM)

  k_cast<<<4096, 256, 0, stream>>>(x, xb, (S_LEN * DIN) / 4);

  // fused QKV: consumes f32 weights directly; V written transposed
  k_gemm<1><<<dim3(96, 8), 256, 0, stream>>>(xb, Wq, Wk, Wv, nullptr, Qb, Kbuf, Vtb);

  k_rope<<<10240, 256, 0, stream>>>(Qb, Kbuf, cosT, sinT);

  k_attn<<<dim3(16, 32), 256, 0, stream>>>(Qb, Kbuf, Vtb, ctxb);

  // out = ctx * Wo (f32 weights direct), f32 out
  k_gemm<0><<<dim3(64, 8), 256, 0, stream>>>(ctxb, Wo, nullptr, nullptr, out,
                                             nullptr, nullptr, nullptr);
}

// Round 5
// 214.609 us; speedup vs baseline: 1.1653x; 1.1653x over previous
//
#include <hip/hip_runtime.h>
#include <hip/hip_bf16.h>

#define S_LEN 1024
#define DIN 4096
#define NH 32
#define NG 8
#define HD 128

typedef __bf16 bf16x8 __attribute__((ext_vector_type(8)));
typedef __bf16 bf16x4 __attribute__((ext_vector_type(4)));
typedef float f32x4 __attribute__((ext_vector_type(4)));

__device__ __forceinline__ void gload_lds16(const void* g, void* l) {
  __builtin_amdgcn_global_load_lds(
      (const __attribute__((address_space(1))) unsigned int*)g,
      (__attribute__((address_space(3))) unsigned int*)l, 16, 0, 0);
}

__device__ __forceinline__ unsigned pack2bf(float a, float b) {
  union { __bf16 h[2]; unsigned u; } x;
  x.h[0] = (__bf16)a; x.h[1] = (__bf16)b;
  return x.u;
}

// ---------------- fused prep: cast x + transpose+cast all weights ----------------
// blocks [0,4096): cast x (float4 -> bf16x4)
// blocks [4096,  8192): Wq tiles -> WqkvT rows [0,4096)
// blocks [8192,  9216): Wk tiles -> WqkvT rows [4096,5120)
// blocks [9216, 10240): Wv tiles -> WqkvT rows [5120,6144)
// blocks [10240,14336): Wo tiles -> WoT
__global__ __launch_bounds__(256) void k_prep(const float* __restrict__ x,
                                              const float* __restrict__ Wq,
                                              const float* __restrict__ Wk,
                                              const float* __restrict__ Wv,
                                              const float* __restrict__ Wo,
                                              __bf16* __restrict__ xb,
                                              __bf16* __restrict__ WqkvT,
                                              __bf16* __restrict__ WoT) {
  __shared__ __bf16 t[64][80];
  const int tid = threadIdx.x;
  int bid = blockIdx.x;
  if (bid < 4096) {
    int i = bid * 256 + tid;
    const float4 v = ((const float4*)x)[i];
    bf16x4 o;
    o.x = (__bf16)v.x; o.y = (__bf16)v.y; o.z = (__bf16)v.z; o.w = (__bf16)v.w;
    ((bf16x4*)xb)[i] = o;
    return;
  }
  bid -= 4096;
  const float* W; __bf16* WT; int N, off, tau;
  if (bid < 4096)       { W = Wq; WT = WqkvT; N = 4096; off = 0;    tau = bid; }
  else if (bid < 5120)  { W = Wk; WT = WqkvT; N = 1024; off = 4096; tau = bid - 4096; }
  else if (bid < 6144)  { W = Wv; WT = WqkvT; N = 1024; off = 5120; tau = bid - 5120; }
  else                  { W = Wo; WT = WoT;   N = 4096; off = 0;    tau = bid - 6144; }
  const int ntx = N >> 6;
  const int n0 = (tau % ntx) * 64, k0 = (tau / ntx) * 64;
#pragma unroll
  for (int p = 0; p < 4; ++p) {
    int kk = p * 16 + (tid >> 4);
    int nn = (tid & 15) * 4;
    const float4 v = *(const float4*)&W[(size_t)(k0 + kk) * N + n0 + nn];
    t[nn + 0][kk] = (__bf16)v.x;
    t[nn + 1][kk] = (__bf16)v.y;
    t[nn + 2][kk] = (__bf16)v.z;
    t[nn + 3][kk] = (__bf16)v.w;
  }
  __syncthreads();
#pragma unroll
  for (int p = 0; p < 2; ++p) {
    int nn = p * 32 + (tid >> 3);
    int kk = (tid & 7) * 8;
    bf16x8 v = *(const bf16x8*)&t[nn][kk];
    *(bf16x8*)&WT[(size_t)(off + n0 + nn) * DIN + k0 + kk] = v;
  }
}

// ---------------- RoPE, vectorized: 4 d-pairs per thread ----------------
// Q rows (s*NH+h) then K rows (s*NG+g); 16 threads per row (d4 = 0..15).
// Note cos/sin tables satisfy cos[s][d+64] == cos[s][d].
__global__ __launch_bounds__(256) void k_rope(__bf16* __restrict__ Q, __bf16* __restrict__ Kb,
                                              const float* __restrict__ cosT,
                                              const float* __restrict__ sinT) {
  int idx = blockIdx.x * 256 + threadIdx.x;
  int d = (idx & 15) * 4;
  int row = idx >> 4;
  __bf16* p; int s;
  if (row < S_LEN * NH) { p = Q + (size_t)row * HD; s = row >> 5; }
  else { int r = row - S_LEN * NH; p = Kb + (size_t)r * HD; s = r >> 3; }
  const float4 c = *(const float4*)&cosT[s * HD + d];
  const float4 sn = *(const float4*)&sinT[s * HD + d];
  bf16x4 a = *(const bf16x4*)&p[d];
  bf16x4 b = *(const bf16x4*)&p[d + 64];
  bf16x4 oa, ob;
  oa.x = (__bf16)((float)a.x * c.x - (float)b.x * sn.x);
  oa.y = (__bf16)((float)a.y * c.y - (float)b.y * sn.y);
  oa.z = (__bf16)((float)a.z * c.z - (float)b.z * sn.z);
  oa.w = (__bf16)((float)a.w * c.w - (float)b.w * sn.w);
  ob.x = (__bf16)((float)b.x * c.x + (float)a.x * sn.x);
  ob.y = (__bf16)((float)b.y * c.y + (float)a.y * sn.y);
  ob.z = (__bf16)((float)b.z * c.z + (float)a.z * sn.z);
  ob.w = (__bf16)((float)b.w * c.w + (float)a.w * sn.w);
  *(bf16x4*)&p[d] = oa;
  *(bf16x4*)&p[d + 64] = ob;
}

// ---------------- GEMM: C(M,N) = A(M,K) * Bt(N,K)^T, bf16 in ----------------
// BM=128, BN=64, BK=64. 4 waves. Round-2 proven layout (0 bank conflicts):
// all LDS writes via global_load_lds DMA, 3-bit XOR chunk swizzle, b128 frag reads.
// NEW: double-buffered + prefetch(t+1) issued before compute(t), 1 barrier/iter.
// MODE 0: f32 C (N=4096). MODE 1: QKV split epilogue (Q,K bf16; V written transposed).
template <int MODE>
__global__ __launch_bounds__(256, 3) void k_gemm(const __bf16* __restrict__ A,
                                                 const __bf16* __restrict__ Bt,
                                                 float* __restrict__ C,
                                                 __bf16* __restrict__ Qb,
                                                 __bf16* __restrict__ Kb,
                                                 __bf16* __restrict__ Vt) {
  __shared__ __bf16 As[2][128 * 64];
  __shared__ __bf16 Bs[2][64 * 64];
  const int bm = blockIdx.y, bn = blockIdx.x;
  const int K = DIN, NT = K / 64;

  const int tid = threadIdx.x, w = tid >> 6;
  const int l = tid & 63, l15 = l & 15, g4 = l >> 4;

  const __bf16* Asrc = A + (size_t)(bm * 128) * K;
  const __bf16* Bsrc = Bt + (size_t)(bn * 64) * K;

  f32x4 acc[2][4];
#pragma unroll
  for (int i = 0; i < 2; ++i)
#pragma unroll
    for (int j = 0; j < 4; ++j)
#pragma unroll
      for (int r = 0; r < 4; ++r) acc[i][j][r] = 0.f;

  auto issueA = [&](int t, __bf16* dst) {
#pragma unroll
    for (int p = 0; p < 4; ++p) {
      int c = p * 256 + tid;
      int row = c >> 3, gc = (c & 7) ^ (row & 7);
      gload_lds16(Asrc + (size_t)row * K + t * 64 + gc * 8, dst + (p * 256 + w * 64) * 8);
    }
  };
  auto issueB = [&](int t, __bf16* dst) {
#pragma unroll
    for (int p = 0; p < 2; ++p) {
      int c = p * 256 + tid;
      int row = c >> 3, gc = (c & 7) ^ (row & 7);
      gload_lds16(Bsrc + (size_t)row * K + t * 64 + gc * 8, dst + (p * 256 + w * 64) * 8);
    }
  };
  auto compute = [&](const __bf16* Ab, const __bf16* Bb) {
    bf16x8 af[2][2], bfr[4][2];
#pragma unroll
    for (int i = 0; i < 2; ++i) {
      int m = w * 32 + i * 16 + l15;
#pragma unroll
      for (int kk = 0; kk < 2; ++kk)
        af[i][kk] = *(const bf16x8*)((const char*)Ab + m * 128 + (((kk * 4 + g4) ^ (m & 7)) << 4));
    }
#pragma unroll
    for (int j = 0; j < 4; ++j) {
      int n = j * 16 + l15;
#pragma unroll
      for (int kk = 0; kk < 2; ++kk)
        bfr[j][kk] = *(const bf16x8*)((const char*)Bb + n * 128 + (((kk * 4 + g4) ^ (n & 7)) << 4));
    }
#pragma unroll
    for (int kk = 0; kk < 2; ++kk)
#pragma unroll
      for (int i = 0; i < 2; ++i)
#pragma unroll
        for (int j = 0; j < 4; ++j)
          acc[i][j] = __builtin_amdgcn_mfma_f32_16x16x32_bf16(af[i][kk], bfr[j][kk], acc[i][j], 0, 0, 0);
  };

  // prologue: stage tile 0 into buffer 0
  issueA(0, As[0]); issueB(0, Bs[0]);
  __syncthreads();

  for (int t = 0; t < NT; t += 2) {
    // buffer 0 holds tile t; prefetch t+1 into buffer 1, compute t
    issueA(t + 1, As[1]); issueB(t + 1, Bs[1]);
    compute(As[0], Bs[0]);
    __syncthreads();   // drains prefetch DMA + all frag reads
    // buffer 1 holds tile t+1; prefetch t+2 into buffer 0, compute t+1
    if (t + 2 < NT) { issueA(t + 2, As[0]); issueB(t + 2, Bs[0]); }
    compute(As[1], Bs[1]);
    __syncthreads();
  }

  // ---- epilogue ----
  if constexpr (MODE == 0) {
#pragma unroll
    for (int i = 0; i < 2; ++i)
#pragma unroll
      for (int j = 0; j < 4; ++j)
#pragma unroll
        for (int r = 0; r < 4; ++r) {
          size_t row = bm * 128 + w * 32 + i * 16 + g4 * 4 + r;
          size_t col = bn * 64 + j * 16 + l15;
          C[row * 4096 + col] = acc[i][j][r];
        }
  } else {
    const int nb0 = bn * 64;
    if (bn < 80) {
      __bf16* dst = (bn < 64) ? Qb : Kb;
      int ldc = (bn < 64) ? 4096 : 1024;
      int coff = (bn < 64) ? 0 : 4096;
#pragma unroll
      for (int i = 0; i < 2; ++i)
#pragma unroll
        for (int j = 0; j < 4; ++j)
#pragma unroll
          for (int r = 0; r < 4; ++r) {
            size_t row = bm * 128 + w * 32 + i * 16 + g4 * 4 + r;
            size_t col = nb0 - coff + j * 16 + l15;
            dst[row * ldc + col] = (__bf16)acc[i][j][r];
          }
    } else {
      // V: write transposed -> Vt[n][s]
#pragma unroll
      for (int i = 0; i < 2; ++i)
#pragma unroll
        for (int j = 0; j < 4; ++j) {
          size_t n = nb0 - 5120 + j * 16 + l15;
          size_t m0 = bm * 128 + w * 32 + i * 16 + g4 * 4;
          bf16x4 v;
          v.x = (__bf16)acc[i][j][0]; v.y = (__bf16)acc[i][j][1];
          v.z = (__bf16)acc[i][j][2]; v.w = (__bf16)acc[i][j][3];
          *(bf16x4*)&Vt[n * 1024 + m0] = v;
        }
    }
  }
}

// ---------------- flash attention (round-2 proven) ----------------
__global__ __launch_bounds__(256) void k_attn(const __bf16* __restrict__ Q,
                                              const __bf16* __restrict__ Kb,
                                              const __bf16* __restrict__ Vt,
                                              __bf16* __restrict__ ctx) {
  __shared__ __align__(16) char lds_raw[65536];
  __bf16* Ks = (__bf16*)lds_raw;
  __bf16* Vs = (__bf16*)(lds_raw + 32768);

  const int h = blockIdx.y, g = h >> 2;
  const int q0 = blockIdx.x * 64;
  const int tid = threadIdx.x, w = tid >> 6, l = tid & 63;
  const int l15 = l & 15, g4 = l >> 4;
  const float scale = 0.08838834764831845f;

  bf16x8 qf[4];
  const int qrow = q0 + w * 16 + l15;
#pragma unroll
  for (int ks = 0; ks < 4; ++ks)
    qf[ks] = *(const bf16x8*)&Q[(size_t)qrow * (NH * HD) + h * HD + ks * 32 + g4 * 8];

  f32x4 acc[8];
#pragma unroll
  for (int i = 0; i < 8; ++i)
#pragma unroll
    for (int r = 0; r < 4; ++r) acc[i][r] = 0.f;
  float m_run = -__builtin_inff(), l_run = 0.f;

  const int ntiles = (q0 + 64 + 127) >> 7;
  for (int kt = 0; kt < ntiles; ++kt) {
    const int kv0 = kt * 128;
#pragma unroll
    for (int p = 0; p < 8; ++p) {
      int c = p * 256 + tid;
      int row = c >> 4, cc = c & 15;
      gload_lds16(&Kb[(size_t)(kv0 + row) * (NG * HD) + g * HD + ((cc ^ (row & 7)) << 3)],
                  &Ks[(p * 256 + w * 64) * 8]);
      gload_lds16(&Vt[(size_t)(g * HD + row) * S_LEN + kv0 + ((cc ^ (row & 7)) << 3)],
                  &Vs[(p * 256 + w * 64) * 8]);
    }
    __syncthreads();

    float sreg[8][4];
    const bool need_mask = (kv0 + 127 > q0);
#pragma unroll
    for (int tf = 0; tf < 8; ++tf) {
      f32x4 sa;
#pragma unroll
      for (int r = 0; r < 4; ++r) sa[r] = 0.f;
      int t_loc = tf * 16 + l15;
#pragma unroll
      for (int ks = 0; ks < 4; ++ks) {
        bf16x8 kf = *(const bf16x8*)((const char*)Ks + t_loc * 256 + (((ks * 4 + g4) ^ (t_loc & 7)) << 4));
        sa = __builtin_amdgcn_mfma_f32_16x16x32_bf16(kf, qf[ks], sa, 0, 0, 0);
      }
#pragma unroll
      for (int r = 0; r < 4; ++r) {
        float v = sa[r] * scale;
        if (need_mask && (kv0 + tf * 16 + g4 * 4 + r) > qrow) v = -__builtin_inff();
        sreg[tf][r] = v;
      }
    }
    float mx = -__builtin_inff();
#pragma unroll
    for (int tf = 0; tf < 8; ++tf)
#pragma unroll
      for (int r = 0; r < 4; ++r) mx = fmaxf(mx, sreg[tf][r]);
    mx = fmaxf(mx, __shfl_xor(mx, 16));
    mx = fmaxf(mx, __shfl_xor(mx, 32));
    const float m_new = fmaxf(m_run, mx);
    const float alpha = __expf(m_run - m_new);
    float ssum = 0.f;
#pragma unroll
    for (int tf = 0; tf < 8; ++tf)
#pragma unroll
      for (int r = 0; r < 4; ++r) {
        sreg[tf][r] = __expf(sreg[tf][r] - m_new);
        ssum += sreg[tf][r];
      }
    ssum += __shfl_xor(ssum, 16);
    ssum += __shfl_xor(ssum, 32);
    l_run = l_run * alpha + ssum;
    m_run = m_new;
    float ar[4];
#pragma unroll
    for (int r = 0; r < 4; ++r) ar[r] = __shfl(alpha, g4 * 4 + r);
#pragma unroll
    for (int nf = 0; nf < 8; ++nf)
#pragma unroll
      for (int r = 0; r < 4; ++r) acc[nf][r] *= ar[r];

    __syncthreads();

    char* pb = lds_raw + w * 4096;
#pragma unroll
    for (int tf = 0; tf < 8; ++tf) {
      int chunkc = 2 * tf + (g4 >> 1);
      int addr = l15 * 256 + ((chunkc ^ (l15 & 7)) << 4) + ((g4 & 1) << 3);
      *(unsigned*)(pb + addr)     = pack2bf(sreg[tf][0], sreg[tf][1]);
      *(unsigned*)(pb + addr + 4) = pack2bf(sreg[tf][2], sreg[tf][3]);
    }
    asm volatile("s_waitcnt lgkmcnt(0)" ::: "memory");
    bf16x8 pf[4];
#pragma unroll
    for (int ks = 0; ks < 4; ++ks)
      pf[ks] = *(const bf16x8*)(pb + l15 * 256 + (((ks * 4 + g4) ^ (l15 & 7)) << 4));
#pragma unroll
    for (int nf = 0; nf < 8; ++nf) {
      int d_loc = nf * 16 + l15;
#pragma unroll
      for (int ks = 0; ks < 4; ++ks) {
        bf16x8 vf = *(const bf16x8*)((const char*)Vs + d_loc * 256 + (((ks * 4 + g4) ^ (d_loc & 7)) << 4));
        acc[nf] = __builtin_amdgcn_mfma_f32_16x16x32_bf16(pf[ks], vf, acc[nf], 0, 0, 0);
      }
    }
    __syncthreads();
  }
  float li[4];
#pragma unroll
  for (int r = 0; r < 4; ++r) li[r] = 1.f / __shfl(l_run, g4 * 4 + r);
#pragma unroll
  for (int nf = 0; nf < 8; ++nf)
#pragma unroll
    for (int r = 0; r < 4; ++r) {
      size_t row = q0 + w * 16 + g4 * 4 + r;
      size_t col = (size_t)h * HD + nf * 16 + l15;
      ctx[row * (NH * HD) + col] = (__bf16)(acc[nf][r] * li[r]);
    }
}

// ---------------- host ----------------
extern "C" void kernel_launch(void* const* d_in, const int* in_sizes, int n_in,
                              void* d_out, int out_size, void* d_ws, size_t ws_size,
                              hipStream_t stream) {
  const float* x    = (const float*)d_in[0];
  const float* cosT = (const float*)d_in[2];
  const float* sinT = (const float*)d_in[3];
  const float* Wq   = (const float*)d_in[4];
  const float* Wk   = (const float*)d_in[5];
  const float* Wv   = (const float*)d_in[6];
  const float* Wo   = (const float*)d_in[7];
  float* out = (float*)d_out;

  char* ws = (char*)d_ws;
  const size_t MB = 1u << 20;
  __bf16* xb    = (__bf16*)(ws + 0);        // 8 MB : x bf16; reused as ctx after QKV
  __bf16* WqkvT = (__bf16*)(ws + 8 * MB);   // 48 MB: [Wq^T|Wk^T|Wv^T] (6144 x 4096)
  __bf16* WoT   = (__bf16*)(ws + 56 * MB);  // 32 MB: Wo^T (4096 x 4096)
  __bf16* Qb    = (__bf16*)(ws + 88 * MB);  // 8 MB : Q, roped in-place
  __bf16* Kbuf  = (__bf16*)(ws + 96 * MB);  // 2 MB : K, roped in-place
  __bf16* Vtb   = (__bf16*)(ws + 98 * MB);  // 2 MB : V^T (direct from epilogue)
  __bf16* ctxb  = (__bf16*)(ws + 0);        // aliases xb

  k_prep<<<14336, 256, 0, stream>>>(x, Wq, Wk, Wv, Wo, xb, WqkvT, WoT);

  // fused QKV: (1024 x 6144), V written transposed
  k_gemm<1><<<dim3(96, 8), 256, 0, stream>>>(xb, WqkvT, nullptr, Qb, Kbuf, Vtb);

  k_rope<<<2560, 256, 0, stream>>>(Qb, Kbuf, cosT, sinT);

  k_attn<<<dim3(16, 32), 256, 0, stream>>>(Qb, Kbuf, Vtb, ctxb);

  // out = ctx * WoT^T (1024 x 4096), f32
  k_gemm<0><<<dim3(64, 8), 256, 0, stream>>>(ctxb, WoT, out, nullptr, nullptr, nullptr);
}